// Round 1
// baseline (953.545 us; speedup 1.0000x reference)
//
#include <hip/hip_runtime.h>
#include <hip/hip_bf16.h>

// DeepPM Transformer encoder layer, fp32 baseline (round 0).
// B=8, L=1024, D=256, H=8 (DH=32), DFF=2048.
// Pipeline:
//   lens       <- mask (format auto-detected: float32 / uint8-bool / int32)
//   qkv        = src @ in_proj_w^T + b                  [8192 x 768]
//   ctx        = attention(qkv, lens)                   [8192 x 256]
//   hatt       = ctx @ out_w^T + out_b                  [8192 x 256]
//   hbuf       = src + hatt @ proj_w^T + proj_b         [8192 x 256]
//   ff1o       = gelu(hbuf @ ff1_w^T + ff1_b)           [8192 x 2048]
//   out        = hbuf + ff1o @ ff2_w^T + ff2_b, zero padded rows
//
// Padded rows (l >= lens[b]) are zeroed at the end, so attention bias for
// padded query rows doesn't matter; valid keys are a contiguous prefix so
// the attention key-loop early-exits at ceil(s/64) tiles.

#define BB   8
#define LL   1024
#define DD   256
#define HHN  8
#define DHH  32
#define DFFN 2048

// ---------------------------------------------------------------------------
// lens[b] = number of valid (non-padded) tokens. Mask format auto-detect:
//   - any byte==0x3F at i%4==3  -> float32 (1.0f = 00 00 80 3F)
//   - else any nonzero byte at i%4!=0 -> uint8 bool
//   - else int32 (covers all-valid-float/int too; 0 bitpattern identical)
// ---------------------------------------------------------------------------
__global__ void compute_lens_kernel(const unsigned char* __restrict__ mb,
                                    int* __restrict__ lens) {
  __shared__ int flag3f, flagNA;
  __shared__ int cnt[BB];
  const int tid = threadIdx.x;
  if (tid == 0) { flag3f = 0; flagNA = 0; }
  if (tid < BB) cnt[tid] = 0;
  __syncthreads();
  for (int i = tid; i < BB * LL; i += blockDim.x) {
    unsigned char v = mb[i];
    if (v) {
      if ((i & 3) == 3 && v == 0x3F) flag3f = 1;
      else if (i & 3) flagNA = 1;
    }
  }
  __syncthreads();
  const bool isfloat = (flag3f != 0);
  const bool isbool  = (!isfloat) && (flagNA != 0);
  if (isbool) {
    for (int i = tid; i < BB * LL; i += blockDim.x)
      if (mb[i] == 0) atomicAdd(&cnt[i >> 10], 1);
  } else {
    const int* mi = (const int*)mb;
    for (int i = tid; i < BB * LL; i += blockDim.x)
      if (mi[i] == 0) atomicAdd(&cnt[i >> 10], 1);
  }
  __syncthreads();
  if (tid < BB) lens[tid] = cnt[tid];
}

// ---------------------------------------------------------------------------
// NT GEMM: C[M,N] = A[M,K] * W[N,K]^T (+ epilogue). 128x128 tile, K-step 16,
// 256 threads, 8x8 accumulator per thread (rows {ty*4+i, 64+ty*4+i}, cols
// {tx*4+j, 64+tx*4+j} -> conflict-free b128 LDS reads).
// EPI: 0 = +bias; 1 = +bias,gelu(exact erf); 2 = +bias+resid;
//      3 = +bias+resid, zero rows with l >= lens[b]
// ---------------------------------------------------------------------------
template <int EPI>
__global__ __launch_bounds__(256) void gemm_nt_128(
    const float* __restrict__ A, const float* __restrict__ W,
    const float* __restrict__ bias, const float* __restrict__ resid,
    float* __restrict__ C, const int M, const int N, const int K,
    const int* __restrict__ lens) {
  __shared__ float As[16][128];
  __shared__ float Bs[16][128];
  const int tid = threadIdx.x;
  const int tx = tid & 15;
  const int ty = tid >> 4;
  const int c0 = blockIdx.x << 7;
  const int r0 = blockIdx.y << 7;
  const int lrow = tid >> 1;        // 0..127
  const int lk = (tid & 1) << 3;    // 0 or 8

  const float* Ap = A + (size_t)(r0 + lrow) * K + lk;
  const float* Wp = W + (size_t)(c0 + lrow) * K + lk;

  float acc[8][8];
#pragma unroll
  for (int i = 0; i < 8; ++i)
#pragma unroll
    for (int j = 0; j < 8; ++j) acc[i][j] = 0.f;

  float4 pa0 = *(const float4*)(Ap);
  float4 pa1 = *(const float4*)(Ap + 4);
  float4 pb0 = *(const float4*)(Wp);
  float4 pb1 = *(const float4*)(Wp + 4);

  const int nkt = K >> 4;
  for (int kt = 0; kt < nkt; ++kt) {
    {
      float sa[8] = {pa0.x, pa0.y, pa0.z, pa0.w, pa1.x, pa1.y, pa1.z, pa1.w};
      float sb[8] = {pb0.x, pb0.y, pb0.z, pb0.w, pb1.x, pb1.y, pb1.z, pb1.w};
#pragma unroll
      for (int i = 0; i < 8; ++i) {
        As[lk + i][lrow] = sa[i];
        Bs[lk + i][lrow] = sb[i];
      }
    }
    __syncthreads();
    if (kt + 1 < nkt) {
      const float* Ap2 = Ap + ((size_t)(kt + 1) << 4);
      const float* Wp2 = Wp + ((size_t)(kt + 1) << 4);
      pa0 = *(const float4*)(Ap2);
      pa1 = *(const float4*)(Ap2 + 4);
      pb0 = *(const float4*)(Wp2);
      pb1 = *(const float4*)(Wp2 + 4);
    }
#pragma unroll
    for (int k = 0; k < 16; ++k) {
      const float4 alo = *(const float4*)&As[k][ty << 2];
      const float4 ahi = *(const float4*)&As[k][64 + (ty << 2)];
      const float4 blo = *(const float4*)&Bs[k][tx << 2];
      const float4 bhi = *(const float4*)&Bs[k][64 + (tx << 2)];
      const float av[8] = {alo.x, alo.y, alo.z, alo.w, ahi.x, ahi.y, ahi.z, ahi.w};
      const float bv[8] = {blo.x, blo.y, blo.z, blo.w, bhi.x, bhi.y, bhi.z, bhi.w};
#pragma unroll
      for (int i = 0; i < 8; ++i)
#pragma unroll
        for (int j = 0; j < 8; ++j)
          acc[i][j] = fmaf(av[i], bv[j], acc[i][j]);
    }
    __syncthreads();
  }

  const float4 bl = *(const float4*)&bias[c0 + (tx << 2)];
  const float4 bh = *(const float4*)&bias[c0 + 64 + (tx << 2)];
  const float bb[8] = {bl.x, bl.y, bl.z, bl.w, bh.x, bh.y, bh.z, bh.w};

#pragma unroll
  for (int i = 0; i < 8; ++i) {
    const int r = r0 + ((i < 4) ? ((ty << 2) + i) : (64 + (ty << 2) + (i - 4)));
    bool zrow = false;
    if (EPI == 3) {
      const int bi = r >> 10;
      const int li = r & (LL - 1);
      zrow = (li >= lens[bi]);
    }
#pragma unroll
    for (int half = 0; half < 2; ++half) {
      const int c = c0 + (half << 6) + (tx << 2);
      float v0 = acc[i][half * 4 + 0] + bb[half * 4 + 0];
      float v1 = acc[i][half * 4 + 1] + bb[half * 4 + 1];
      float v2 = acc[i][half * 4 + 2] + bb[half * 4 + 2];
      float v3 = acc[i][half * 4 + 3] + bb[half * 4 + 3];
      if (EPI == 1) {
        v0 = 0.5f * v0 * (1.0f + erff(v0 * 0.70710678118654752f));
        v1 = 0.5f * v1 * (1.0f + erff(v1 * 0.70710678118654752f));
        v2 = 0.5f * v2 * (1.0f + erff(v2 * 0.70710678118654752f));
        v3 = 0.5f * v3 * (1.0f + erff(v3 * 0.70710678118654752f));
      }
      if (EPI >= 2) {
        const float4 rv = *(const float4*)&resid[(size_t)r * N + c];
        v0 += rv.x; v1 += rv.y; v2 += rv.z; v3 += rv.w;
      }
      if (EPI == 3 && zrow) { v0 = v1 = v2 = v3 = 0.f; }
      float4 ov;
      ov.x = v0; ov.y = v1; ov.z = v2; ov.w = v3;
      *(float4*)&C[(size_t)r * N + c] = ov;
    }
  }
}

// ---------------------------------------------------------------------------
// Flash-style attention, fp32. Grid (L/64, H, B), 256 threads.
// 4 threads per query row (key partitions p=0..3), K/V tiles of 64 keys in
// padded LDS [64][36] (conflict-free for the p-strided row reads).
// Online softmax with per-16-key chunks; shfl_xor butterfly merge at end.
// Bias: (s - |i-j|)/s for valid i,j; 0 for padded-query rows; keys >= s
// masked with -1e30 (valid keys are a contiguous prefix -> early exit).
// ---------------------------------------------------------------------------
__global__ __launch_bounds__(256) void attn_fwd(const float* __restrict__ qkv,
                                                float* __restrict__ ctx,
                                                const int* __restrict__ lens) {
  const int tid = threadIdx.x;
  const int ql = tid >> 2;
  const int p = tid & 3;
  const int qi = (blockIdx.x << 6) + ql;
  const int hh = blockIdx.y;
  const int b = blockIdx.z;

  __shared__ float Ks[64][36];
  __shared__ float Vs[64][36];

  const int slen = lens[b];
  const float sf = (float)slen;
  const float inv_s = 1.0f / sf;
  const bool qvalid = (qi < slen);

  const float scale = 0.17677669529663689f;  // 1/sqrt(32)
  float q[32];
  {
    const float* qp = qkv + (size_t)(b * LL + qi) * 768 + hh * DHH;
#pragma unroll
    for (int d = 0; d < 32; d += 4) {
      const float4 t = *(const float4*)(qp + d);
      q[d + 0] = t.x * scale;
      q[d + 1] = t.y * scale;
      q[d + 2] = t.z * scale;
      q[d + 3] = t.w * scale;
    }
  }

  float o[32];
#pragma unroll
  for (int d = 0; d < 32; ++d) o[d] = 0.f;
  float m = -1e30f, l = 0.f;

  const int lj = tid >> 2;         // 0..63 (row to stage)
  const int ldd = (tid & 3) << 3;  // 0,8,16,24
  const int ntk = (slen + 63) >> 6;

  for (int kt = 0; kt < ntk; ++kt) {
    __syncthreads();
    {
      const float* kb =
          qkv + (size_t)(b * LL + (kt << 6) + lj) * 768 + 256 + hh * DHH + ldd;
      const float4 k0 = *(const float4*)(kb);
      const float4 k1 = *(const float4*)(kb + 4);
      const float4 v0 = *(const float4*)(kb + 256);
      const float4 v1 = *(const float4*)(kb + 260);
      *(float4*)&Ks[lj][ldd] = k0;
      *(float4*)&Ks[lj][ldd + 4] = k1;
      *(float4*)&Vs[lj][ldd] = v0;
      *(float4*)&Vs[lj][ldd + 4] = v1;
    }
    __syncthreads();

    float sc[16];
#pragma unroll
    for (int jj = 0; jj < 16; ++jj) {
      const int j = (jj << 2) + p;
      const float* kr = &Ks[j][0];
      float a0 = 0.f, a1 = 0.f;
#pragma unroll
      for (int d = 0; d < 32; d += 8) {
        const float4 kA = *(const float4*)(kr + d);
        const float4 kB = *(const float4*)(kr + d + 4);
        a0 = fmaf(q[d + 0], kA.x, a0);
        a0 = fmaf(q[d + 1], kA.y, a0);
        a0 = fmaf(q[d + 2], kA.z, a0);
        a0 = fmaf(q[d + 3], kA.w, a0);
        a1 = fmaf(q[d + 4], kB.x, a1);
        a1 = fmaf(q[d + 5], kB.y, a1);
        a1 = fmaf(q[d + 6], kB.z, a1);
        a1 = fmaf(q[d + 7], kB.w, a1);
      }
      const float accv = a0 + a1;
      const int kj = (kt << 6) + j;
      if (kj < slen) {
        sc[jj] = accv + (qvalid ? (sf - fabsf((float)(qi - kj))) * inv_s : 0.f);
      } else {
        sc[jj] = -1e30f;
      }
    }
    float cm = sc[0];
#pragma unroll
    for (int jj = 1; jj < 16; ++jj) cm = fmaxf(cm, sc[jj]);
    const float mn = fmaxf(m, cm);
    const float corr = __expf(m - mn);
    float psum = 0.f;
#pragma unroll
    for (int jj = 0; jj < 16; ++jj) {
      sc[jj] = __expf(sc[jj] - mn);
      psum += sc[jj];
    }
    l = l * corr + psum;
#pragma unroll
    for (int d = 0; d < 32; ++d) o[d] *= corr;
#pragma unroll
    for (int jj = 0; jj < 16; ++jj) {
      const int j = (jj << 2) + p;
      const float* vr = &Vs[j][0];
      const float pw = sc[jj];
#pragma unroll
      for (int d = 0; d < 32; d += 4) {
        const float4 vv = *(const float4*)(vr + d);
        o[d + 0] = fmaf(pw, vv.x, o[d + 0]);
        o[d + 1] = fmaf(pw, vv.y, o[d + 1]);
        o[d + 2] = fmaf(pw, vv.z, o[d + 2]);
        o[d + 3] = fmaf(pw, vv.w, o[d + 3]);
      }
    }
    m = mn;
  }

  // merge the 4 key-partition partials (lanes ql*4 + p, p in 0..3)
#pragma unroll
  for (int msk = 1; msk <= 2; msk <<= 1) {
    const float m2 = __shfl_xor(m, msk);
    const float l2 = __shfl_xor(l, msk);
    const float mn = fmaxf(m, m2);
    const float s1 = __expf(m - mn);
    const float s2 = __expf(m2 - mn);
    l = l * s1 + l2 * s2;
#pragma unroll
    for (int d = 0; d < 32; ++d) {
      const float o2 = __shfl_xor(o[d], msk);
      o[d] = o[d] * s1 + o2 * s2;
    }
    m = mn;
  }

  const float invl = 1.0f / l;
  // lane p writes dims [p*8, p*8+8) -- static-index selection (no scratch)
  float ow[8];
#pragma unroll
  for (int k = 0; k < 8; ++k) {
    const float va = (p & 1) ? o[8 + k] : o[k];
    const float vb = (p & 1) ? o[24 + k] : o[16 + k];
    ow[k] = ((p & 2) ? vb : va) * invl;
  }
  float* op = ctx + (size_t)(b * LL + qi) * 256 + hh * DHH + (p << 3);
  float4 w0, w1;
  w0.x = ow[0]; w0.y = ow[1]; w0.z = ow[2]; w0.w = ow[3];
  w1.x = ow[4]; w1.y = ow[5]; w1.z = ow[6]; w1.w = ow[7];
  *(float4*)op = w0;
  *(float4*)(op + 4) = w1;
}

// ---------------------------------------------------------------------------
extern "C" void kernel_launch(void* const* d_in, const int* in_sizes, int n_in,
                              void* d_out, int out_size, void* d_ws,
                              size_t ws_size, hipStream_t stream) {
  (void)in_sizes; (void)n_in; (void)out_size; (void)ws_size;
  const float* src = (const float*)d_in[0];
  const unsigned char* mask = (const unsigned char*)d_in[1];
  const float* in_proj_w = (const float*)d_in[2];
  const float* in_proj_b = (const float*)d_in[3];
  const float* out_w = (const float*)d_in[4];
  const float* out_b = (const float*)d_in[5];
  const float* proj_w = (const float*)d_in[6];
  const float* proj_b = (const float*)d_in[7];
  const float* ff1_w = (const float*)d_in[8];
  const float* ff1_b = (const float*)d_in[9];
  const float* ff2_w = (const float*)d_in[10];
  const float* ff2_b = (const float*)d_in[11];
  float* out = (float*)d_out;
  float* ws = (float*)d_ws;

  const int M = BB * LL;  // 8192
  float* qkv = ws;                           // M*768  = 6291456
  float* ctx = qkv + (size_t)M * 768;        // M*256
  float* hatt = ctx + (size_t)M * 256;       // M*256
  float* hbuf = hatt + (size_t)M * 256;      // M*256
  float* ff1o = hbuf + (size_t)M * 256;      // M*2048
  int* lens = (int*)(ff1o + (size_t)M * 2048);

  compute_lens_kernel<<<1, 256, 0, stream>>>(mask, lens);
  // qkv = src @ in_proj_w^T + in_proj_b
  gemm_nt_128<0><<<dim3(6, 64), 256, 0, stream>>>(src, in_proj_w, in_proj_b,
                                                  nullptr, qkv, M, 768, 256,
                                                  nullptr);
  // ctx = attention(qkv)
  attn_fwd<<<dim3(LL / 64, HHN, BB), 256, 0, stream>>>(qkv, ctx, lens);
  // hatt = ctx @ out_w^T + out_b
  gemm_nt_128<0><<<dim3(2, 64), 256, 0, stream>>>(ctx, out_w, out_b, nullptr,
                                                  hatt, M, 256, 256, nullptr);
  // hbuf = src + hatt @ proj_w^T + proj_b
  gemm_nt_128<2><<<dim3(2, 64), 256, 0, stream>>>(hatt, proj_w, proj_b, src,
                                                  hbuf, M, 256, 256, nullptr);
  // ff1o = gelu(hbuf @ ff1_w^T + ff1_b)
  gemm_nt_128<1><<<dim3(16, 64), 256, 0, stream>>>(hbuf, ff1_w, ff1_b, nullptr,
                                                   ff1o, M, 2048, 256, nullptr);
  // out = hbuf + ff1o @ ff2_w^T + ff2_b, zero padded rows
  gemm_nt_128<3><<<dim3(2, 64), 256, 0, stream>>>(ff1o, ff2_w, ff2_b, hbuf, out,
                                                  M, 256, 2048, lens);
}

// Round 2
// 510.512 us; speedup vs baseline: 1.8678x; 1.8678x over previous
//
#include <hip/hip_runtime.h>
#include <hip/hip_bf16.h>

// DeepPM Transformer encoder layer (round 1): fp32 GEMMs + bf16-MFMA flash attn.
// B=8, L=1024, D=256, H=8 (DH=32), DFF=2048.

#define BB   8
#define LL   1024
#define DD   256
#define HHN  8
#define DHH  32
#define DFFN 2048

typedef __attribute__((ext_vector_type(8))) __bf16 bf16x8;
typedef __attribute__((ext_vector_type(4))) float f32x4;

// ---------------------------------------------------------------------------
// lens[b] = number of valid tokens (mask format auto-detected).
// ---------------------------------------------------------------------------
__global__ void compute_lens_kernel(const unsigned char* __restrict__ mb,
                                    int* __restrict__ lens) {
  __shared__ int flag3f, flagNA;
  __shared__ int cnt[BB];
  const int tid = threadIdx.x;
  if (tid == 0) { flag3f = 0; flagNA = 0; }
  if (tid < BB) cnt[tid] = 0;
  __syncthreads();
  for (int i = tid; i < BB * LL; i += blockDim.x) {
    unsigned char v = mb[i];
    if (v) {
      if ((i & 3) == 3 && v == 0x3F) flag3f = 1;
      else if (i & 3) flagNA = 1;
    }
  }
  __syncthreads();
  const bool isfloat = (flag3f != 0);
  const bool isbool  = (!isfloat) && (flagNA != 0);
  if (isbool) {
    for (int i = tid; i < BB * LL; i += blockDim.x)
      if (mb[i] == 0) atomicAdd(&cnt[i >> 10], 1);
  } else {
    const int* mi = (const int*)mb;
    for (int i = tid; i < BB * LL; i += blockDim.x)
      if (mi[i] == 0) atomicAdd(&cnt[i >> 10], 1);
  }
  __syncthreads();
  if (tid < BB) lens[tid] = cnt[tid];
}

// ---------------------------------------------------------------------------
// NT GEMM: C[M,N] = A[M,K] * W[N,K]^T (+ epilogue), fp32, 128x128 tile.
// EPI: 0 = +bias; 1 = +bias,gelu; 2 = +bias+resid; 3 = +bias+resid,zero pad rows
// ---------------------------------------------------------------------------
template <int EPI>
__global__ __launch_bounds__(256) void gemm_nt_128(
    const float* __restrict__ A, const float* __restrict__ W,
    const float* __restrict__ bias, const float* __restrict__ resid,
    float* __restrict__ C, const int M, const int N, const int K,
    const int* __restrict__ lens) {
  __shared__ float As[16][128];
  __shared__ float Bs[16][128];
  const int tid = threadIdx.x;
  const int tx = tid & 15;
  const int ty = tid >> 4;
  const int c0 = blockIdx.x << 7;
  const int r0 = blockIdx.y << 7;
  const int lrow = tid >> 1;
  const int lk = (tid & 1) << 3;

  const float* Ap = A + (size_t)(r0 + lrow) * K + lk;
  const float* Wp = W + (size_t)(c0 + lrow) * K + lk;

  float acc[8][8];
#pragma unroll
  for (int i = 0; i < 8; ++i)
#pragma unroll
    for (int j = 0; j < 8; ++j) acc[i][j] = 0.f;

  float4 pa0 = *(const float4*)(Ap);
  float4 pa1 = *(const float4*)(Ap + 4);
  float4 pb0 = *(const float4*)(Wp);
  float4 pb1 = *(const float4*)(Wp + 4);

  const int nkt = K >> 4;
  for (int kt = 0; kt < nkt; ++kt) {
    {
      float sa[8] = {pa0.x, pa0.y, pa0.z, pa0.w, pa1.x, pa1.y, pa1.z, pa1.w};
      float sb[8] = {pb0.x, pb0.y, pb0.z, pb0.w, pb1.x, pb1.y, pb1.z, pb1.w};
#pragma unroll
      for (int i = 0; i < 8; ++i) {
        As[lk + i][lrow] = sa[i];
        Bs[lk + i][lrow] = sb[i];
      }
    }
    __syncthreads();
    if (kt + 1 < nkt) {
      const float* Ap2 = Ap + ((size_t)(kt + 1) << 4);
      const float* Wp2 = Wp + ((size_t)(kt + 1) << 4);
      pa0 = *(const float4*)(Ap2);
      pa1 = *(const float4*)(Ap2 + 4);
      pb0 = *(const float4*)(Wp2);
      pb1 = *(const float4*)(Wp2 + 4);
    }
#pragma unroll
    for (int k = 0; k < 16; ++k) {
      const float4 alo = *(const float4*)&As[k][ty << 2];
      const float4 ahi = *(const float4*)&As[k][64 + (ty << 2)];
      const float4 blo = *(const float4*)&Bs[k][tx << 2];
      const float4 bhi = *(const float4*)&Bs[k][64 + (tx << 2)];
      const float av[8] = {alo.x, alo.y, alo.z, alo.w, ahi.x, ahi.y, ahi.z, ahi.w};
      const float bv[8] = {blo.x, blo.y, blo.z, blo.w, bhi.x, bhi.y, bhi.z, bhi.w};
#pragma unroll
      for (int i = 0; i < 8; ++i)
#pragma unroll
        for (int j = 0; j < 8; ++j)
          acc[i][j] = fmaf(av[i], bv[j], acc[i][j]);
    }
    __syncthreads();
  }

  const float4 bl = *(const float4*)&bias[c0 + (tx << 2)];
  const float4 bh = *(const float4*)&bias[c0 + 64 + (tx << 2)];
  const float bb[8] = {bl.x, bl.y, bl.z, bl.w, bh.x, bh.y, bh.z, bh.w};

#pragma unroll
  for (int i = 0; i < 8; ++i) {
    const int r = r0 + ((i < 4) ? ((ty << 2) + i) : (64 + (ty << 2) + (i - 4)));
    bool zrow = false;
    if (EPI == 3) {
      const int bi = r >> 10;
      const int li = r & (LL - 1);
      zrow = (li >= lens[bi]);
    }
#pragma unroll
    for (int half = 0; half < 2; ++half) {
      const int c = c0 + (half << 6) + (tx << 2);
      float v0 = acc[i][half * 4 + 0] + bb[half * 4 + 0];
      float v1 = acc[i][half * 4 + 1] + bb[half * 4 + 1];
      float v2 = acc[i][half * 4 + 2] + bb[half * 4 + 2];
      float v3 = acc[i][half * 4 + 3] + bb[half * 4 + 3];
      if (EPI == 1) {
        v0 = 0.5f * v0 * (1.0f + erff(v0 * 0.70710678118654752f));
        v1 = 0.5f * v1 * (1.0f + erff(v1 * 0.70710678118654752f));
        v2 = 0.5f * v2 * (1.0f + erff(v2 * 0.70710678118654752f));
        v3 = 0.5f * v3 * (1.0f + erff(v3 * 0.70710678118654752f));
      }
      if (EPI >= 2) {
        const float4 rv = *(const float4*)&resid[(size_t)r * N + c];
        v0 += rv.x; v1 += rv.y; v2 += rv.z; v3 += rv.w;
      }
      if (EPI == 3 && zrow) { v0 = v1 = v2 = v3 = 0.f; }
      float4 ov;
      ov.x = v0; ov.y = v1; ov.z = v2; ov.w = v3;
      *(float4*)&C[(size_t)r * N + c] = ov;
    }
  }
}

// ---------------------------------------------------------------------------
// MFMA bf16 flash attention. Grid (L/64, H, B), 256 threads = 4 waves.
// Wave w owns q-rows [q0+16w, q0+16w+16). Per 64-key tile:
//   4x mfma_f32_16x16x32_bf16 (QK^T, full DH=32 as the K-dim)
//   online softmax in-register (shfl_xor over 16-lane column groups)
//   P (bf16) -> wave-private LDS; 4x MFMA for PV (V staged transposed).
// A/B fragments use a consistent slot->k addressing on both operands, so the
// HW k-slot permutation cancels; only C/D layout (col=lane&15, row=4*(l>>4)+i)
// is assumed (HW-verified mapping).
// LDS strides: K rows 56 bf16 (112B), V^T/P rows 72 bf16 (144B) -> the
// b128 fragment reads are 2-way-bank-aliased max (free).
// ---------------------------------------------------------------------------
__global__ __launch_bounds__(256) void attn_fwd_mfma(
    const float* __restrict__ qkv, float* __restrict__ ctx,
    const int* __restrict__ lens) {
  __shared__ __bf16 Ks[64][56];
  __shared__ __bf16 Vt[32][72];
  __shared__ __bf16 Pl[4][16][72];

  const int tid = threadIdx.x;
  const int q0 = blockIdx.x << 6;
  const int hh = blockIdx.y;
  const int b = blockIdx.z;
  const int slen = lens[b];
  if (q0 >= slen) return;  // padded q rows are zeroed downstream

  const int w = tid >> 6;
  const int lane = tid & 63;
  const int c = lane & 15;
  const int h = lane >> 4;
  const int h8 = h << 3;

  const float sf = (float)slen;
  const float inv_s = 1.0f / sf;
  const float scale = 0.17677669529663689f;  // 1/sqrt(32)

  // Q fragment (row = c, k-slots = h8..h8+7), pre-scaled
  bf16x8 qf;
  {
    const int qrow = q0 + (w << 4) + c;
    const float* qp = qkv + (size_t)(b * LL + qrow) * 768 + hh * DHH + h8;
    const float4 qa = *(const float4*)qp;
    const float4 qb = *(const float4*)(qp + 4);
    const float qs[8] = {qa.x, qa.y, qa.z, qa.w, qb.x, qb.y, qb.z, qb.w};
#pragma unroll
    for (int j = 0; j < 8; ++j) qf[j] = (__bf16)(qs[j] * scale);
  }

  f32x4 acc0 = {0.f, 0.f, 0.f, 0.f};
  f32x4 acc1 = {0.f, 0.f, 0.f, 0.f};
  float mrow[4] = {-1e30f, -1e30f, -1e30f, -1e30f};
  float lrow[4] = {0.f, 0.f, 0.f, 0.f};

  const int skey = tid >> 2;        // staging: key row 0..63
  const int sdg = (tid & 3) << 3;   // staging: dh group 0,8,16,24
  const int ntk = (slen + 63) >> 6;
  const int qg = q0 + (w << 4) + (h << 2);  // global q row for reg i=0

  for (int kt = 0; kt < ntk; ++kt) {
    const int kbase = kt << 6;
    __syncthreads();
    // ---- stage K (row-major) and V (transposed) as bf16 ----
    {
      const float* kb =
          qkv + (size_t)(b * LL + kbase + skey) * 768 + 256 + hh * DHH + sdg;
      const float4 k0 = *(const float4*)kb;
      const float4 k1 = *(const float4*)(kb + 4);
      const float kvs[8] = {k0.x, k0.y, k0.z, k0.w, k1.x, k1.y, k1.z, k1.w};
      bf16x8 kw;
#pragma unroll
      for (int j = 0; j < 8; ++j) kw[j] = (__bf16)kvs[j];
      *(bf16x8*)&Ks[skey][sdg] = kw;

      const float4 v0 = *(const float4*)(kb + 256);
      const float4 v1 = *(const float4*)(kb + 260);
      const float vvs[8] = {v0.x, v0.y, v0.z, v0.w, v1.x, v1.y, v1.z, v1.w};
#pragma unroll
      for (int j = 0; j < 8; ++j) Vt[sdg + j][skey] = (__bf16)vvs[j];
    }
    __syncthreads();

    // ---- QK^T: 4 MFMAs -> S[16q x 64k] ----
    f32x4 st[4];
#pragma unroll
    for (int t = 0; t < 4; ++t) {
      const bf16x8 kf = *(const bf16x8*)&Ks[(t << 4) + c][h8];
      st[t] = __builtin_amdgcn_mfma_f32_16x16x32_bf16(
          qf, kf, (f32x4){0.f, 0.f, 0.f, 0.f}, 0, 0, 0);
    }

    // ---- bias + mask ----
    float v[4][4];  // [t][i]
#pragma unroll
    for (int t = 0; t < 4; ++t) {
      const int kj = kbase + (t << 4) + c;
      const bool kvalid = kj < slen;
      const float kjf = (float)kj;
#pragma unroll
      for (int i = 0; i < 4; ++i) {
        const float dist = fabsf((float)(qg + i) - kjf);
        v[t][i] = kvalid ? (st[t][i] + (sf - dist) * inv_s) : -1e30f;
      }
    }

    // ---- online softmax (row stats shared across the 16-lane col group) ----
#pragma unroll
    for (int i = 0; i < 4; ++i) {
      float mx = fmaxf(fmaxf(v[0][i], v[1][i]), fmaxf(v[2][i], v[3][i]));
      mx = fmaxf(mx, __shfl_xor(mx, 1));
      mx = fmaxf(mx, __shfl_xor(mx, 2));
      mx = fmaxf(mx, __shfl_xor(mx, 4));
      mx = fmaxf(mx, __shfl_xor(mx, 8));
      const float mnew = fmaxf(mrow[i], mx);
      const float corr = __expf(mrow[i] - mnew);
      mrow[i] = mnew;
      float ps = 0.f;
#pragma unroll
      for (int t = 0; t < 4; ++t) {
        const float p = __expf(v[t][i] - mnew);
        ps += p;
        Pl[w][(h << 2) + i][c + (t << 4)] = (__bf16)p;
      }
      ps += __shfl_xor(ps, 1);
      ps += __shfl_xor(ps, 2);
      ps += __shfl_xor(ps, 4);
      ps += __shfl_xor(ps, 8);
      lrow[i] = lrow[i] * corr + ps;
      acc0[i] *= corr;
      acc1[i] *= corr;
    }

    // wave-local: P writes must land before fragment reads
    asm volatile("s_waitcnt lgkmcnt(0)" ::: "memory");

    // ---- PV: ctx[16q x 32d] += P[16x64] * V[64x32] ----
#pragma unroll
    for (int n = 0; n < 2; ++n) {
      const bf16x8 pf = *(const bf16x8*)&Pl[w][c][h8 + (n << 5)];
      const bf16x8 vf0 = *(const bf16x8*)&Vt[c][h8 + (n << 5)];
      const bf16x8 vf1 = *(const bf16x8*)&Vt[16 + c][h8 + (n << 5)];
      acc0 = __builtin_amdgcn_mfma_f32_16x16x32_bf16(pf, vf0, acc0, 0, 0, 0);
      acc1 = __builtin_amdgcn_mfma_f32_16x16x32_bf16(pf, vf1, acc1, 0, 0, 0);
    }
  }

  // ---- epilogue: divide by row sum, write ctx ----
#pragma unroll
  for (int i = 0; i < 4; ++i) {
    const float il = 1.0f / lrow[i];
    float* op =
        ctx + (size_t)(b * LL + q0 + (w << 4) + (h << 2) + i) * 256 + hh * DHH;
    op[c] = acc0[i] * il;
    op[c + 16] = acc1[i] * il;
  }
}

// ---------------------------------------------------------------------------
extern "C" void kernel_launch(void* const* d_in, const int* in_sizes, int n_in,
                              void* d_out, int out_size, void* d_ws,
                              size_t ws_size, hipStream_t stream) {
  (void)in_sizes; (void)n_in; (void)out_size; (void)ws_size;
  const float* src = (const float*)d_in[0];
  const unsigned char* mask = (const unsigned char*)d_in[1];
  const float* in_proj_w = (const float*)d_in[2];
  const float* in_proj_b = (const float*)d_in[3];
  const float* out_w = (const float*)d_in[4];
  const float* out_b = (const float*)d_in[5];
  const float* proj_w = (const float*)d_in[6];
  const float* proj_b = (const float*)d_in[7];
  const float* ff1_w = (const float*)d_in[8];
  const float* ff1_b = (const float*)d_in[9];
  const float* ff2_w = (const float*)d_in[10];
  const float* ff2_b = (const float*)d_in[11];
  float* out = (float*)d_out;
  float* ws = (float*)d_ws;

  const int M = BB * LL;  // 8192
  float* qkv = ws;                           // M*768
  float* ctx = qkv + (size_t)M * 768;        // M*256
  float* hatt = ctx + (size_t)M * 256;       // M*256
  float* hbuf = hatt + (size_t)M * 256;      // M*256
  float* ff1o = hbuf + (size_t)M * 256;      // M*2048
  int* lens = (int*)(ff1o + (size_t)M * 2048);

  compute_lens_kernel<<<1, 256, 0, stream>>>(mask, lens);
  gemm_nt_128<0><<<dim3(6, 64), 256, 0, stream>>>(src, in_proj_w, in_proj_b,
                                                  nullptr, qkv, M, 768, 256,
                                                  nullptr);
  attn_fwd_mfma<<<dim3(LL / 64, HHN, BB), 256, 0, stream>>>(qkv, ctx, lens);
  gemm_nt_128<0><<<dim3(2, 64), 256, 0, stream>>>(ctx, out_w, out_b, nullptr,
                                                  hatt, M, 256, 256, nullptr);
  gemm_nt_128<2><<<dim3(2, 64), 256, 0, stream>>>(hatt, proj_w, proj_b, src,
                                                  hbuf, M, 256, 256, nullptr);
  gemm_nt_128<1><<<dim3(16, 64), 256, 0, stream>>>(hbuf, ff1_w, ff1_b, nullptr,
                                                   ff1o, M, 2048, 256, nullptr);
  gemm_nt_128<3><<<dim3(2, 64), 256, 0, stream>>>(ff1o, ff2_w, ff2_b, hbuf, out,
                                                  M, 256, 2048, lens);
}

// Round 3
// 171.499 us; speedup vs baseline: 5.5601x; 2.9768x over previous
//
#include <hip/hip_runtime.h>
#include <hip/hip_bf16.h>

// DeepPM Transformer encoder layer (round 2): bf16-MFMA everywhere.
// B=8, L=1024, D=256, H=8 (DH=32), DFF=2048.
// Pipeline:
//   lens; convert {src, in_proj_w, ff1_w, ff2_w} -> bf16; Wc = proj_w@out_w (bf16),
//   bc = proj_w@out_b + proj_b
//   qkv_bf  = src_bf @ in_proj_bf^T + in_proj_b          (bf16 out)
//   ctx_bf  = mfma flash attention(qkv_bf)               (bf16 out)
//   hbuf    = src + ctx_bf @ Wc^T + bc                   (fp32 + bf16 out)
//   ff1o_bf = gelu(hbuf_bf @ ff1_bf^T + ff1_b)           (bf16 out)
//   out     = hbuf_f32 + ff1o_bf @ ff2_bf^T + ff2_b, zero padded rows (fp32)

#define BB   8
#define LL   1024
#define DD   256
#define HHN  8
#define DHH  32
#define DFFN 2048

typedef __attribute__((ext_vector_type(8))) __bf16 bf16x8;
typedef __attribute__((ext_vector_type(4))) float f32x4;

__device__ inline void gload16(const void* g, void* l) {
  __builtin_amdgcn_global_load_lds(
      (const __attribute__((address_space(1))) void*)g,
      (__attribute__((address_space(3))) void*)l, 16, 0, 0);
}

// ---------------------------------------------------------------------------
__global__ void compute_lens_kernel(const unsigned char* __restrict__ mb,
                                    int* __restrict__ lens) {
  __shared__ int flag3f, flagNA;
  __shared__ int cnt[BB];
  const int tid = threadIdx.x;
  if (tid == 0) { flag3f = 0; flagNA = 0; }
  if (tid < BB) cnt[tid] = 0;
  __syncthreads();
  for (int i = tid; i < BB * LL; i += blockDim.x) {
    unsigned char v = mb[i];
    if (v) {
      if ((i & 3) == 3 && v == 0x3F) flag3f = 1;
      else if (i & 3) flagNA = 1;
    }
  }
  __syncthreads();
  const bool isfloat = (flag3f != 0);
  const bool isbool  = (!isfloat) && (flagNA != 0);
  if (isbool) {
    for (int i = tid; i < BB * LL; i += blockDim.x)
      if (mb[i] == 0) atomicAdd(&cnt[i >> 10], 1);
  } else {
    const int* mi = (const int*)mb;
    for (int i = tid; i < BB * LL; i += blockDim.x)
      if (mi[i] == 0) atomicAdd(&cnt[i >> 10], 1);
  }
  __syncthreads();
  if (tid < BB) lens[tid] = cnt[tid];
}

// ---------------------------------------------------------------------------
// Fused fp32->bf16 conversion of 4 arrays (all sizes divisible by 8).
// ---------------------------------------------------------------------------
__global__ __launch_bounds__(256) void cvt4_kernel(
    const float* __restrict__ s0, __hip_bfloat16* __restrict__ d0, int n0,
    const float* __restrict__ s1, __hip_bfloat16* __restrict__ d1, int n1,
    const float* __restrict__ s2, __hip_bfloat16* __restrict__ d2, int n2,
    const float* __restrict__ s3, __hip_bfloat16* __restrict__ d3, int n3) {
  int i = (blockIdx.x * 256 + threadIdx.x) * 8;
  const float* s;
  __hip_bfloat16* d;
  if (i < n0) { s = s0; d = d0; }
  else if (i < n0 + n1) { s = s1; d = d1; i -= n0; }
  else if (i < n0 + n1 + n2) { s = s2; d = d2; i -= n0 + n1; }
  else if (i < n0 + n1 + n2 + n3) { s = s3; d = d3; i -= n0 + n1 + n2; }
  else return;
  const float4 a = *(const float4*)(s + i);
  const float4 b = *(const float4*)(s + i + 4);
  bf16x8 o;
  o[0] = (__bf16)a.x; o[1] = (__bf16)a.y; o[2] = (__bf16)a.z; o[3] = (__bf16)a.w;
  o[4] = (__bf16)b.x; o[5] = (__bf16)b.y; o[6] = (__bf16)b.z; o[7] = (__bf16)b.w;
  *(bf16x8*)(d + i) = o;
}

// ---------------------------------------------------------------------------
// Wc[i,k] = sum_n proj_w[i,n]*out_w[n,k] (bf16); bc[i] = proj_b[i] + proj_w[i,:]@out_b
// ---------------------------------------------------------------------------
__global__ __launch_bounds__(256) void wc_kernel(
    const float* __restrict__ proj_w, const float* __restrict__ out_w,
    const float* __restrict__ proj_b, const float* __restrict__ out_b,
    __hip_bfloat16* __restrict__ Wc, float* __restrict__ bc) {
  const int i = blockIdx.x;
  const int k = threadIdx.x;
  float acc = 0.f;
#pragma unroll 4
  for (int n = 0; n < DD; ++n)
    acc = fmaf(proj_w[i * DD + n], out_w[n * DD + k], acc);
  Wc[i * DD + k] = (__hip_bfloat16)acc;
  __shared__ float red[DD];
  red[k] = proj_w[i * DD + k] * out_b[k];
  __syncthreads();
  for (int sft = 128; sft > 0; sft >>= 1) {
    if (k < sft) red[k] += red[k + sft];
    __syncthreads();
  }
  if (k == 0) bc[i] = proj_b[i] + red[0];
}

// ---------------------------------------------------------------------------
// bf16 MFMA NT GEMM (m97 structure): C = A[M,K]_bf16 @ W[N,K]_bf16^T + epi.
// Tile BM x 128, BK=32, 256 threads = 4 waves (2x2), per-wave (BM/2) x 64.
// global_load_lds width-16 staging into double-buffered LDS; one barrier/iter.
// EPI: 0 = +bias -> bf16; 1 = +bias,gelu -> bf16;
//      2 = +bias+resid(f32) -> f32 AND bf16; 3 = +bias+resid(f32),zero pad -> f32
// ---------------------------------------------------------------------------
template <int EPI, int BM>
__global__ __launch_bounds__(256) void gemm_bf16(
    const __hip_bfloat16* __restrict__ A, const __hip_bfloat16* __restrict__ W,
    const float* __restrict__ bias, const float* __restrict__ resid,
    float* __restrict__ Cf, __hip_bfloat16* __restrict__ Cb, const int M,
    const int N, const int K, const int* __restrict__ lens) {
  constexpr int MF = BM / 32;  // m-fragments per wave
  constexpr int CH = BM / 64;  // 4KB staging chunks for A
  __shared__ __bf16 As[2][BM][32];
  __shared__ __bf16 Bs[2][128][32];

  const int tid = threadIdx.x;
  const int w = tid >> 6;
  const int lane = tid & 63;
  const int c = lane & 15;
  const int hq = lane >> 4;
  const int h8 = hq << 3;
  const int wr = w >> 1, wc = w & 1;
  const int c0 = blockIdx.x << 7;
  const int r0 = blockIdx.y * BM;
  const int srow = tid >> 2;
  const int scol = (tid & 3) << 3;

  auto STAGE = [&](int buf, int kt) {
    const int k0 = kt << 5;
#pragma unroll
    for (int ch = 0; ch < CH; ++ch)
      gload16(A + (size_t)(r0 + (ch << 6) + srow) * K + k0 + scol,
              &As[buf][(ch << 6) + (w << 4)][0]);
#pragma unroll
    for (int ch = 0; ch < 2; ++ch)
      gload16(W + (size_t)(c0 + (ch << 6) + srow) * K + k0 + scol,
              &Bs[buf][(ch << 6) + (w << 4)][0]);
  };

  f32x4 acc[MF][4];
#pragma unroll
  for (int m = 0; m < MF; ++m)
#pragma unroll
    for (int n = 0; n < 4; ++n) acc[m][n] = (f32x4){0.f, 0.f, 0.f, 0.f};

  const int nkt = K >> 5;
  int buf = 0;
  STAGE(0, 0);
  __syncthreads();
  for (int kt = 0; kt < nkt; ++kt) {
    if (kt + 1 < nkt) STAGE(buf ^ 1, kt + 1);
    bf16x8 af[MF], bfr[4];
#pragma unroll
    for (int m = 0; m < MF; ++m)
      af[m] = *(const bf16x8*)&As[buf][wr * (MF * 16) + (m << 4) + c][h8];
#pragma unroll
    for (int n = 0; n < 4; ++n)
      bfr[n] = *(const bf16x8*)&Bs[buf][(wc << 6) + (n << 4) + c][h8];
#pragma unroll
    for (int m = 0; m < MF; ++m)
#pragma unroll
      for (int n = 0; n < 4; ++n)
        acc[m][n] =
            __builtin_amdgcn_mfma_f32_16x16x32_bf16(af[m], bfr[n], acc[m][n], 0, 0, 0);
    __syncthreads();
    buf ^= 1;
  }

  // epilogue
  float bv[4];
#pragma unroll
  for (int n = 0; n < 4; ++n) bv[n] = bias[c0 + (wc << 6) + (n << 4) + c];
  const int mylen = (EPI == 3) ? lens[r0 >> 10] : 0;

#pragma unroll
  for (int m = 0; m < MF; ++m) {
#pragma unroll
    for (int i = 0; i < 4; ++i) {
      const int gr = r0 + wr * (MF * 16) + (m << 4) + (hq << 2) + i;
      const bool zrow = (EPI == 3) && ((gr & (LL - 1)) >= mylen);
#pragma unroll
      for (int n = 0; n < 4; ++n) {
        const int gc = c0 + (wc << 6) + (n << 4) + c;
        float v = acc[m][n][i] + bv[n];
        if (EPI == 1) v = 0.5f * v * (1.0f + erff(v * 0.70710678118654752f));
        if (EPI >= 2) v += resid[(size_t)gr * N + gc];
        if (EPI == 3 && zrow) v = 0.f;
        if (EPI == 2 || EPI == 3) Cf[(size_t)gr * N + gc] = v;
        if (EPI != 3) Cb[(size_t)gr * N + gc] = (__hip_bfloat16)v;
      }
    }
  }
}

// ---------------------------------------------------------------------------
// MFMA bf16 flash attention (bf16 qkv in, bf16 ctx out). Grid (L/64, H, B).
// ---------------------------------------------------------------------------
__global__ __launch_bounds__(256) void attn_fwd_mfma(
    const __hip_bfloat16* __restrict__ qkv, __hip_bfloat16* __restrict__ ctx,
    const int* __restrict__ lens) {
  __shared__ __bf16 Ks[64][56];
  __shared__ __bf16 Vt[32][72];
  __shared__ __bf16 Pl[4][16][72];

  const int tid = threadIdx.x;
  const int q0 = blockIdx.x << 6;
  const int hh = blockIdx.y;
  const int b = blockIdx.z;
  const int slen = lens[b];
  if (q0 >= slen) return;  // padded q rows are zeroed downstream

  const int w = tid >> 6;
  const int lane = tid & 63;
  const int c = lane & 15;
  const int h = lane >> 4;
  const int h8 = h << 3;

  const float sf = (float)slen;
  const float inv_s = 1.0f / sf;
  const float scale = 0.17677669529663689f;  // 1/sqrt(32)

  bf16x8 qf;
  {
    const int qrow = q0 + (w << 4) + c;
    const bf16x8 qraw =
        *(const bf16x8*)(qkv + (size_t)(b * LL + qrow) * 768 + hh * DHH + h8);
#pragma unroll
    for (int j = 0; j < 8; ++j) qf[j] = (__bf16)((float)qraw[j] * scale);
  }

  f32x4 acc0 = {0.f, 0.f, 0.f, 0.f};
  f32x4 acc1 = {0.f, 0.f, 0.f, 0.f};
  float mrow[4] = {-1e30f, -1e30f, -1e30f, -1e30f};
  float lrow[4] = {0.f, 0.f, 0.f, 0.f};

  const int skey = tid >> 2;
  const int sdg = (tid & 3) << 3;
  const int ntk = (slen + 63) >> 6;
  const int qg = q0 + (w << 4) + (h << 2);

  for (int kt = 0; kt < ntk; ++kt) {
    const int kbase = kt << 6;
    __syncthreads();
    {
      const __hip_bfloat16* kb =
          qkv + (size_t)(b * LL + kbase + skey) * 768 + 256 + hh * DHH + sdg;
      *(bf16x8*)&Ks[skey][sdg] = *(const bf16x8*)kb;
      const bf16x8 vv = *(const bf16x8*)(kb + 256);
#pragma unroll
      for (int j = 0; j < 8; ++j) Vt[sdg + j][skey] = vv[j];
    }
    __syncthreads();

    f32x4 st[4];
#pragma unroll
    for (int t = 0; t < 4; ++t) {
      const bf16x8 kf = *(const bf16x8*)&Ks[(t << 4) + c][h8];
      st[t] = __builtin_amdgcn_mfma_f32_16x16x32_bf16(
          qf, kf, (f32x4){0.f, 0.f, 0.f, 0.f}, 0, 0, 0);
    }

    float v[4][4];
#pragma unroll
    for (int t = 0; t < 4; ++t) {
      const int kj = kbase + (t << 4) + c;
      const bool kvalid = kj < slen;
      const float kjf = (float)kj;
#pragma unroll
      for (int i = 0; i < 4; ++i) {
        const float dist = fabsf((float)(qg + i) - kjf);
        v[t][i] = kvalid ? (st[t][i] + (sf - dist) * inv_s) : -1e30f;
      }
    }

#pragma unroll
    for (int i = 0; i < 4; ++i) {
      float mx = fmaxf(fmaxf(v[0][i], v[1][i]), fmaxf(v[2][i], v[3][i]));
      mx = fmaxf(mx, __shfl_xor(mx, 1));
      mx = fmaxf(mx, __shfl_xor(mx, 2));
      mx = fmaxf(mx, __shfl_xor(mx, 4));
      mx = fmaxf(mx, __shfl_xor(mx, 8));
      const float mnew = fmaxf(mrow[i], mx);
      const float corr = __expf(mrow[i] - mnew);
      mrow[i] = mnew;
      float ps = 0.f;
#pragma unroll
      for (int t = 0; t < 4; ++t) {
        const float p = __expf(v[t][i] - mnew);
        ps += p;
        Pl[w][(h << 2) + i][c + (t << 4)] = (__bf16)p;
      }
      ps += __shfl_xor(ps, 1);
      ps += __shfl_xor(ps, 2);
      ps += __shfl_xor(ps, 4);
      ps += __shfl_xor(ps, 8);
      lrow[i] = lrow[i] * corr + ps;
      acc0[i] *= corr;
      acc1[i] *= corr;
    }

    asm volatile("s_waitcnt lgkmcnt(0)" ::: "memory");

#pragma unroll
    for (int n = 0; n < 2; ++n) {
      const bf16x8 pf = *(const bf16x8*)&Pl[w][c][h8 + (n << 5)];
      const bf16x8 vf0 = *(const bf16x8*)&Vt[c][h8 + (n << 5)];
      const bf16x8 vf1 = *(const bf16x8*)&Vt[16 + c][h8 + (n << 5)];
      acc0 = __builtin_amdgcn_mfma_f32_16x16x32_bf16(pf, vf0, acc0, 0, 0, 0);
      acc1 = __builtin_amdgcn_mfma_f32_16x16x32_bf16(pf, vf1, acc1, 0, 0, 0);
    }
  }

#pragma unroll
  for (int i = 0; i < 4; ++i) {
    const float il = 1.0f / lrow[i];
    __hip_bfloat16* op =
        ctx + (size_t)(b * LL + q0 + (w << 4) + (h << 2) + i) * 256 + hh * DHH;
    op[c] = (__hip_bfloat16)(acc0[i] * il);
    op[c + 16] = (__hip_bfloat16)(acc1[i] * il);
  }
}

// ---------------------------------------------------------------------------
extern "C" void kernel_launch(void* const* d_in, const int* in_sizes, int n_in,
                              void* d_out, int out_size, void* d_ws,
                              size_t ws_size, hipStream_t stream) {
  (void)in_sizes; (void)n_in; (void)out_size; (void)ws_size;
  const float* src = (const float*)d_in[0];
  const unsigned char* mask = (const unsigned char*)d_in[1];
  const float* in_proj_w = (const float*)d_in[2];
  const float* in_proj_b = (const float*)d_in[3];
  const float* out_w = (const float*)d_in[4];
  const float* out_b = (const float*)d_in[5];
  const float* proj_w = (const float*)d_in[6];
  const float* proj_b = (const float*)d_in[7];
  const float* ff1_w = (const float*)d_in[8];
  const float* ff1_b = (const float*)d_in[9];
  const float* ff2_w = (const float*)d_in[10];
  const float* ff2_b = (const float*)d_in[11];
  float* out = (float*)d_out;

  const int M = BB * LL;  // 8192
  char* p = (char*)d_ws;
  __hip_bfloat16* qkv_bf = (__hip_bfloat16*)p; p += (size_t)M * 768 * 2;
  __hip_bfloat16* ctx_bf = (__hip_bfloat16*)p; p += (size_t)M * 256 * 2;
  float* hbuf_f = (float*)p;                   p += (size_t)M * 256 * 4;
  __hip_bfloat16* hbuf_bf = (__hip_bfloat16*)p; p += (size_t)M * 256 * 2;
  __hip_bfloat16* ff1o_bf = (__hip_bfloat16*)p; p += (size_t)M * 2048 * 2;
  __hip_bfloat16* src_bf = (__hip_bfloat16*)p;  p += (size_t)M * 256 * 2;
  __hip_bfloat16* wqkv_bf = (__hip_bfloat16*)p; p += (size_t)768 * 256 * 2;
  __hip_bfloat16* wff1_bf = (__hip_bfloat16*)p; p += (size_t)2048 * 256 * 2;
  __hip_bfloat16* wff2_bf = (__hip_bfloat16*)p; p += (size_t)256 * 2048 * 2;
  __hip_bfloat16* wc_bf = (__hip_bfloat16*)p;   p += (size_t)256 * 256 * 2;
  float* bc = (float*)p;                        p += 256 * 4;
  int* lens = (int*)p;

  compute_lens_kernel<<<1, 256, 0, stream>>>(mask, lens);
  {
    const int n0 = M * 256, n1 = 768 * 256, n2 = 2048 * 256, n3 = 256 * 2048;
    const int nb = (n0 + n1 + n2 + n3) / 8 / 256;
    cvt4_kernel<<<nb, 256, 0, stream>>>(src, src_bf, n0, in_proj_w, wqkv_bf, n1,
                                        ff1_w, wff1_bf, n2, ff2_w, wff2_bf, n3);
  }
  wc_kernel<<<256, 256, 0, stream>>>(proj_w, out_w, proj_b, out_b, wc_bf, bc);

  // qkv = src @ in_proj^T + b   [8192 x 768], bf16 out
  gemm_bf16<0, 128><<<dim3(6, 64), 256, 0, stream>>>(
      src_bf, wqkv_bf, in_proj_b, nullptr, nullptr, qkv_bf, M, 768, 256, nullptr);
  // attention
  attn_fwd_mfma<<<dim3(LL / 64, HHN, BB), 256, 0, stream>>>(qkv_bf, ctx_bf, lens);
  // hbuf = src + ctx @ Wc^T + bc   [8192 x 256], f32 + bf16 out
  gemm_bf16<2, 64><<<dim3(2, 128), 256, 0, stream>>>(
      ctx_bf, wc_bf, bc, src, hbuf_f, hbuf_bf, M, 256, 256, nullptr);
  // ff1o = gelu(hbuf @ ff1^T + b)  [8192 x 2048], bf16 out
  gemm_bf16<1, 128><<<dim3(16, 64), 256, 0, stream>>>(
      hbuf_bf, wff1_bf, ff1_b, nullptr, nullptr, ff1o_bf, M, 2048, 256, nullptr);
  // out = hbuf + ff1o @ ff2^T + b, zero padded rows  [8192 x 256], f32 out
  gemm_bf16<3, 64><<<dim3(2, 128), 256, 0, stream>>>(
      ff1o_bf, wff2_bf, ff2_b, hbuf_f, out, nullptr, M, 256, 2048, lens);
}

// Round 4
// 156.581 us; speedup vs baseline: 6.0898x; 1.0953x over previous
//
#include <hip/hip_runtime.h>
#include <hip/hip_bf16.h>

// DeepPM Transformer encoder layer (round 3): bf16 MFMA everywhere;
// attention: static-max softmax (shift-invariant, m=8), conflict-free V^T
// (stride 66), register-double-buffered K/V staging.
// B=8, L=1024, D=256, H=8 (DH=32), DFF=2048.

#define BB   8
#define LL   1024
#define DD   256
#define HHN  8
#define DHH  32
#define DFFN 2048

typedef __attribute__((ext_vector_type(8))) __bf16 bf16x8;
typedef __attribute__((ext_vector_type(4))) float f32x4;

__device__ inline void gload16(const void* g, void* l) {
  __builtin_amdgcn_global_load_lds(
      (const __attribute__((address_space(1))) void*)g,
      (__attribute__((address_space(3))) void*)l, 16, 0, 0);
}

// ---------------------------------------------------------------------------
__global__ void compute_lens_kernel(const unsigned char* __restrict__ mb,
                                    int* __restrict__ lens) {
  __shared__ int flag3f, flagNA;
  __shared__ int cnt[BB];
  const int tid = threadIdx.x;
  if (tid == 0) { flag3f = 0; flagNA = 0; }
  if (tid < BB) cnt[tid] = 0;
  __syncthreads();
  for (int i = tid; i < BB * LL; i += blockDim.x) {
    unsigned char v = mb[i];
    if (v) {
      if ((i & 3) == 3 && v == 0x3F) flag3f = 1;
      else if (i & 3) flagNA = 1;
    }
  }
  __syncthreads();
  const bool isfloat = (flag3f != 0);
  const bool isbool  = (!isfloat) && (flagNA != 0);
  if (isbool) {
    for (int i = tid; i < BB * LL; i += blockDim.x)
      if (mb[i] == 0) atomicAdd(&cnt[i >> 10], 1);
  } else {
    const int* mi = (const int*)mb;
    for (int i = tid; i < BB * LL; i += blockDim.x)
      if (mi[i] == 0) atomicAdd(&cnt[i >> 10], 1);
  }
  __syncthreads();
  if (tid < BB) lens[tid] = cnt[tid];
}

// ---------------------------------------------------------------------------
// Fused fp32->bf16 conversion of 4 arrays (all sizes divisible by 8).
// ---------------------------------------------------------------------------
__global__ __launch_bounds__(256) void cvt4_kernel(
    const float* __restrict__ s0, __hip_bfloat16* __restrict__ d0, int n0,
    const float* __restrict__ s1, __hip_bfloat16* __restrict__ d1, int n1,
    const float* __restrict__ s2, __hip_bfloat16* __restrict__ d2, int n2,
    const float* __restrict__ s3, __hip_bfloat16* __restrict__ d3, int n3) {
  int i = (blockIdx.x * 256 + threadIdx.x) * 8;
  const float* s;
  __hip_bfloat16* d;
  if (i < n0) { s = s0; d = d0; }
  else if (i < n0 + n1) { s = s1; d = d1; i -= n0; }
  else if (i < n0 + n1 + n2) { s = s2; d = d2; i -= n0 + n1; }
  else if (i < n0 + n1 + n2 + n3) { s = s3; d = d3; i -= n0 + n1 + n2; }
  else return;
  const float4 a = *(const float4*)(s + i);
  const float4 b = *(const float4*)(s + i + 4);
  bf16x8 o;
  o[0] = (__bf16)a.x; o[1] = (__bf16)a.y; o[2] = (__bf16)a.z; o[3] = (__bf16)a.w;
  o[4] = (__bf16)b.x; o[5] = (__bf16)b.y; o[6] = (__bf16)b.z; o[7] = (__bf16)b.w;
  *(bf16x8*)(d + i) = o;
}

// ---------------------------------------------------------------------------
// Wc[i,k] = sum_n proj_w[i,n]*out_w[n,k] (bf16); bc[i] = proj_b[i] + proj_w[i,:]@out_b
// ---------------------------------------------------------------------------
__global__ __launch_bounds__(256) void wc_kernel(
    const float* __restrict__ proj_w, const float* __restrict__ out_w,
    const float* __restrict__ proj_b, const float* __restrict__ out_b,
    __hip_bfloat16* __restrict__ Wc, float* __restrict__ bc) {
  const int i = blockIdx.x;
  const int k = threadIdx.x;
  float acc = 0.f;
#pragma unroll 4
  for (int n = 0; n < DD; ++n)
    acc = fmaf(proj_w[i * DD + n], out_w[n * DD + k], acc);
  Wc[i * DD + k] = (__hip_bfloat16)acc;
  __shared__ float red[DD];
  red[k] = proj_w[i * DD + k] * out_b[k];
  __syncthreads();
  for (int sft = 128; sft > 0; sft >>= 1) {
    if (k < sft) red[k] += red[k + sft];
    __syncthreads();
  }
  if (k == 0) bc[i] = proj_b[i] + red[0];
}

// ---------------------------------------------------------------------------
// bf16 MFMA NT GEMM (m97 structure): C = A[M,K]_bf16 @ W[N,K]_bf16^T + epi.
// EPI: 0 = +bias -> bf16; 1 = +bias,gelu -> bf16;
//      2 = +bias+resid(f32) -> f32 AND bf16; 3 = +bias+resid(f32),zero pad -> f32
// ---------------------------------------------------------------------------
template <int EPI, int BM>
__global__ __launch_bounds__(256) void gemm_bf16(
    const __hip_bfloat16* __restrict__ A, const __hip_bfloat16* __restrict__ W,
    const float* __restrict__ bias, const float* __restrict__ resid,
    float* __restrict__ Cf, __hip_bfloat16* __restrict__ Cb, const int M,
    const int N, const int K, const int* __restrict__ lens) {
  constexpr int MF = BM / 32;
  constexpr int CH = BM / 64;
  __shared__ __bf16 As[2][BM][32];
  __shared__ __bf16 Bs[2][128][32];

  const int tid = threadIdx.x;
  const int w = tid >> 6;
  const int lane = tid & 63;
  const int c = lane & 15;
  const int hq = lane >> 4;
  const int h8 = hq << 3;
  const int wr = w >> 1, wc = w & 1;
  const int c0 = blockIdx.x << 7;
  const int r0 = blockIdx.y * BM;
  const int srow = tid >> 2;
  const int scol = (tid & 3) << 3;

  auto STAGE = [&](int buf, int kt) {
    const int k0 = kt << 5;
#pragma unroll
    for (int ch = 0; ch < CH; ++ch)
      gload16(A + (size_t)(r0 + (ch << 6) + srow) * K + k0 + scol,
              &As[buf][(ch << 6) + (w << 4)][0]);
#pragma unroll
    for (int ch = 0; ch < 2; ++ch)
      gload16(W + (size_t)(c0 + (ch << 6) + srow) * K + k0 + scol,
              &Bs[buf][(ch << 6) + (w << 4)][0]);
  };

  f32x4 acc[MF][4];
#pragma unroll
  for (int m = 0; m < MF; ++m)
#pragma unroll
    for (int n = 0; n < 4; ++n) acc[m][n] = (f32x4){0.f, 0.f, 0.f, 0.f};

  const int nkt = K >> 5;
  int buf = 0;
  STAGE(0, 0);
  __syncthreads();
  for (int kt = 0; kt < nkt; ++kt) {
    if (kt + 1 < nkt) STAGE(buf ^ 1, kt + 1);
    bf16x8 af[MF], bfr[4];
#pragma unroll
    for (int m = 0; m < MF; ++m)
      af[m] = *(const bf16x8*)&As[buf][wr * (MF * 16) + (m << 4) + c][h8];
#pragma unroll
    for (int n = 0; n < 4; ++n)
      bfr[n] = *(const bf16x8*)&Bs[buf][(wc << 6) + (n << 4) + c][h8];
#pragma unroll
    for (int m = 0; m < MF; ++m)
#pragma unroll
      for (int n = 0; n < 4; ++n)
        acc[m][n] =
            __builtin_amdgcn_mfma_f32_16x16x32_bf16(af[m], bfr[n], acc[m][n], 0, 0, 0);
    __syncthreads();
    buf ^= 1;
  }

  float bv[4];
#pragma unroll
  for (int n = 0; n < 4; ++n) bv[n] = bias[c0 + (wc << 6) + (n << 4) + c];
  const int mylen = (EPI == 3) ? lens[r0 >> 10] : 0;

#pragma unroll
  for (int m = 0; m < MF; ++m) {
#pragma unroll
    for (int i = 0; i < 4; ++i) {
      const int gr = r0 + wr * (MF * 16) + (m << 4) + (hq << 2) + i;
      const bool zrow = (EPI == 3) && ((gr & (LL - 1)) >= mylen);
#pragma unroll
      for (int n = 0; n < 4; ++n) {
        const int gc = c0 + (wc << 6) + (n << 4) + c;
        float v = acc[m][n][i] + bv[n];
        if (EPI == 1) v = 0.5f * v * (1.0f + erff(v * 0.70710678118654752f));
        if (EPI >= 2) v += resid[(size_t)gr * N + gc];
        if (EPI == 3 && zrow) v = 0.f;
        if (EPI == 2 || EPI == 3) Cf[(size_t)gr * N + gc] = v;
        if (EPI != 3) Cb[(size_t)gr * N + gc] = (__hip_bfloat16)v;
      }
    }
  }
}

// ---------------------------------------------------------------------------
// MFMA bf16 flash attention, static-max softmax (m = 8, shift-invariant).
// Grid (L/64, H, B), 256 threads = 4 waves, wave w owns q rows [q0+16w, +16).
// Per 64-key tile: 4 QK MFMAs, exp2-based P (no cross-lane, no rescale),
// P->LDS (conflict-free), 4 PV MFMAs. l reduced once at the end.
// Vt stride 66 bf16 (132B = 33 banks): transpose scalar writes are 2-way
// (free); vf fragment reads as 4x ds_read_b32 (conflict-free).
// K/V global loads register-double-buffered (latency hidden under compute).
// ---------------------------------------------------------------------------
__global__ __launch_bounds__(256) void attn_fwd_mfma(
    const __hip_bfloat16* __restrict__ qkv, __hip_bfloat16* __restrict__ ctx,
    const int* __restrict__ lens) {
  __shared__ __bf16 Ks[64][56];
  __shared__ __bf16 Vt[32][66];
  __shared__ __bf16 Pl[4][16][72];

  const int tid = threadIdx.x;
  const int q0 = blockIdx.x << 6;
  const int hh = blockIdx.y;
  const int b = blockIdx.z;
  const int slen = lens[b];
  if (q0 >= slen) return;  // padded q rows are zeroed downstream

  const int w = tid >> 6;
  const int lane = tid & 63;
  const int c = lane & 15;
  const int h = lane >> 4;
  const int h8 = h << 3;

  const float L2E = 1.44269504f;
  const float sf = (float)slen;
  const float cb = -7.0f * L2E;          // (bias_const 1 - moff 8) * log2e
  const float cd = (1.0f / sf) * L2E;    // dist coefficient * log2e
  const float qscale = 0.17677669529663689f * L2E;  // 1/sqrt(32) * log2e

  // Q fragment (row c, k-slots h8..h8+7), pre-scaled by qscale
  bf16x8 qf;
  {
    const int qrow = q0 + (w << 4) + c;
    const bf16x8 qraw =
        *(const bf16x8*)(qkv + (size_t)(b * LL + qrow) * 768 + hh * DHH + h8);
#pragma unroll
    for (int j = 0; j < 8; ++j) qf[j] = (__bf16)((float)qraw[j] * qscale);
  }

  f32x4 acc0 = {0.f, 0.f, 0.f, 0.f};
  f32x4 acc1 = {0.f, 0.f, 0.f, 0.f};
  float lsum[4] = {0.f, 0.f, 0.f, 0.f};

  const int skey = tid >> 2;        // staging: key row 0..63
  const int sdg = (tid & 3) << 3;   // staging: dh group 0,8,16,24
  const int ntk = (slen + 63) >> 6;
  const int qg = q0 + (w << 4) + (h << 2);  // global q row for reg i=0

  bf16x8 kreg, vreg;
  {
    const __hip_bfloat16* kb =
        qkv + (size_t)(b * LL + skey) * 768 + 256 + hh * DHH + sdg;
    kreg = *(const bf16x8*)kb;
    vreg = *(const bf16x8*)(kb + 256);
  }

  for (int kt = 0; kt < ntk; ++kt) {
    const int kbase = kt << 6;
    __syncthreads();  // previous tile's compute done; LDS reusable
    *(bf16x8*)&Ks[skey][sdg] = kreg;
#pragma unroll
    for (int j = 0; j < 8; ++j) Vt[sdg + j][skey] = vreg[j];
    if (kt + 1 < ntk) {  // prefetch next tile (latency hidden under compute)
      const __hip_bfloat16* kb =
          qkv + (size_t)(b * LL + kbase + 64 + skey) * 768 + 256 + hh * DHH + sdg;
      kreg = *(const bf16x8*)kb;
      vreg = *(const bf16x8*)(kb + 256);
    }
    __syncthreads();  // staging visible

    // ---- QK^T: 4 MFMAs -> S*log2e [16q x 64k] ----
    f32x4 st[4];
#pragma unroll
    for (int t = 0; t < 4; ++t) {
      const bf16x8 kf = *(const bf16x8*)&Ks[(t << 4) + c][h8];
      st[t] = __builtin_amdgcn_mfma_f32_16x16x32_bf16(
          qf, kf, (f32x4){0.f, 0.f, 0.f, 0.f}, 0, 0, 0);
    }

    // ---- static-max softmax: p = exp2(S*l2e + cb - dist*cd) ----
#pragma unroll
    for (int t = 0; t < 4; ++t) {
      const int kj = kbase + (t << 4) + c;
      const bool kvalid = kj < slen;
      const float kjf = (float)kj;
#pragma unroll
      for (int i = 0; i < 4; ++i) {
        const float dist = fabsf((float)(qg + i) - kjf);
        const float arg = kvalid ? (st[t][i] + cb - dist * cd) : -1e30f;
        const float p = __builtin_amdgcn_exp2f(arg);
        lsum[i] += p;
        Pl[w][(h << 2) + i][c + (t << 4)] = (__bf16)p;
      }
    }

    // wave-local: P writes must land before fragment reads
    asm volatile("s_waitcnt lgkmcnt(0)" ::: "memory");

    // ---- PV: ctx[16q x 32d] += P[16x64] * V[64x32] ----
#pragma unroll
    for (int n = 0; n < 2; ++n) {
      const bf16x8 pf = *(const bf16x8*)&Pl[w][c][h8 + (n << 5)];
      // vf reads: 4x b32 each (Vt rows are 132B-strided; 4B aligned)
      const uint32_t* v0p = (const uint32_t*)&Vt[c][h8 + (n << 5)];
      const uint32_t* v1p = (const uint32_t*)&Vt[16 + c][h8 + (n << 5)];
      union { uint32_t u[4]; bf16x8 v; } t0, t1;
#pragma unroll
      for (int j = 0; j < 4; ++j) { t0.u[j] = v0p[j]; t1.u[j] = v1p[j]; }
      acc0 = __builtin_amdgcn_mfma_f32_16x16x32_bf16(pf, t0.v, acc0, 0, 0, 0);
      acc1 = __builtin_amdgcn_mfma_f32_16x16x32_bf16(pf, t1.v, acc1, 0, 0, 0);
    }
  }

  // ---- final l reduction (once) + epilogue ----
#pragma unroll
  for (int i = 0; i < 4; ++i) {
    float l = lsum[i];
    l += __shfl_xor(l, 1);
    l += __shfl_xor(l, 2);
    l += __shfl_xor(l, 4);
    l += __shfl_xor(l, 8);
    const float il = 1.0f / l;
    __hip_bfloat16* op =
        ctx + (size_t)(b * LL + q0 + (w << 4) + (h << 2) + i) * 256 + hh * DHH;
    op[c] = (__hip_bfloat16)(acc0[i] * il);
    op[c + 16] = (__hip_bfloat16)(acc1[i] * il);
  }
}

// ---------------------------------------------------------------------------
extern "C" void kernel_launch(void* const* d_in, const int* in_sizes, int n_in,
                              void* d_out, int out_size, void* d_ws,
                              size_t ws_size, hipStream_t stream) {
  (void)in_sizes; (void)n_in; (void)out_size; (void)ws_size;
  const float* src = (const float*)d_in[0];
  const unsigned char* mask = (const unsigned char*)d_in[1];
  const float* in_proj_w = (const float*)d_in[2];
  const float* in_proj_b = (const float*)d_in[3];
  const float* out_w = (const float*)d_in[4];
  const float* out_b = (const float*)d_in[5];
  const float* proj_w = (const float*)d_in[6];
  const float* proj_b = (const float*)d_in[7];
  const float* ff1_w = (const float*)d_in[8];
  const float* ff1_b = (const float*)d_in[9];
  const float* ff2_w = (const float*)d_in[10];
  const float* ff2_b = (const float*)d_in[11];
  float* out = (float*)d_out;

  const int M = BB * LL;  // 8192
  char* p = (char*)d_ws;
  __hip_bfloat16* qkv_bf = (__hip_bfloat16*)p; p += (size_t)M * 768 * 2;
  __hip_bfloat16* ctx_bf = (__hip_bfloat16*)p; p += (size_t)M * 256 * 2;
  float* hbuf_f = (float*)p;                   p += (size_t)M * 256 * 4;
  __hip_bfloat16* hbuf_bf = (__hip_bfloat16*)p; p += (size_t)M * 256 * 2;
  __hip_bfloat16* ff1o_bf = (__hip_bfloat16*)p; p += (size_t)M * 2048 * 2;
  __hip_bfloat16* src_bf = (__hip_bfloat16*)p;  p += (size_t)M * 256 * 2;
  __hip_bfloat16* wqkv_bf = (__hip_bfloat16*)p; p += (size_t)768 * 256 * 2;
  __hip_bfloat16* wff1_bf = (__hip_bfloat16*)p; p += (size_t)2048 * 256 * 2;
  __hip_bfloat16* wff2_bf = (__hip_bfloat16*)p; p += (size_t)256 * 2048 * 2;
  __hip_bfloat16* wc_bf = (__hip_bfloat16*)p;   p += (size_t)256 * 256 * 2;
  float* bc = (float*)p;                        p += 256 * 4;
  int* lens = (int*)p;

  compute_lens_kernel<<<1, 256, 0, stream>>>(mask, lens);
  {
    const int n0 = M * 256, n1 = 768 * 256, n2 = 2048 * 256, n3 = 256 * 2048;
    const int nb = (n0 + n1 + n2 + n3) / 8 / 256;
    cvt4_kernel<<<nb, 256, 0, stream>>>(src, src_bf, n0, in_proj_w, wqkv_bf, n1,
                                        ff1_w, wff1_bf, n2, ff2_w, wff2_bf, n3);
  }
  wc_kernel<<<256, 256, 0, stream>>>(proj_w, out_w, proj_b, out_b, wc_bf, bc);

  // qkv = src @ in_proj^T + b   [8192 x 768], bf16 out
  gemm_bf16<0, 128><<<dim3(6, 64), 256, 0, stream>>>(
      src_bf, wqkv_bf, in_proj_b, nullptr, nullptr, qkv_bf, M, 768, 256, nullptr);
  // attention
  attn_fwd_mfma<<<dim3(LL / 64, HHN, BB), 256, 0, stream>>>(qkv_bf, ctx_bf, lens);
  // hbuf = src + ctx @ Wc^T + bc   [8192 x 256], f32 + bf16 out
  gemm_bf16<2, 64><<<dim3(2, 128), 256, 0, stream>>>(
      ctx_bf, wc_bf, bc, src, hbuf_f, hbuf_bf, M, 256, 256, nullptr);
  // ff1o = gelu(hbuf @ ff1^T + b)  [8192 x 2048], bf16 out
  gemm_bf16<1, 128><<<dim3(16, 64), 256, 0, stream>>>(
      hbuf_bf, wff1_bf, ff1_b, nullptr, nullptr, ff1o_bf, M, 2048, 256, nullptr);
  // out = hbuf + ff1o @ ff2^T + b, zero padded rows  [8192 x 256], f32 out
  gemm_bf16<3, 64><<<dim3(2, 128), 256, 0, stream>>>(
      ff1o_bf, wff2_bf, ff2_b, hbuf_f, out, nullptr, M, 256, 2048, lens);
}